// Round 1
// baseline (294.954 us; speedup 1.0000x reference)
//
#include <hip/hip_runtime.h>

// Problem constants
#define BQ 8
#define NATOM 512
#define NFEAT 42
#define NNEIGH 100
#define H1 64
#define H2 32

// native clang vector (required by __builtin_nontemporal_load)
typedef float vf4 __attribute__((ext_vector_type(4)));

// ws layout (floats):
//   [0, 172368)            padded dE, shape (B, NATOM+1, NFEAT), row 0 per image zeroed
//   [172368, 172368+4096)  Ei in f32 (for Etot reduction)
#define WS_DE 0
#define WS_EI (BQ * (NATOM + 1) * NFEAT)

// ---------------------------------------------------------------- kernel 1
// 512 blocks x 256 threads; 8 atoms per block (all same type since 8 | 256);
// wave w handles atoms 2w, 2w+1 with DUAL accumulators -> each W0s/W1s LDS
// read feeds two FMAs, and weight staging traffic is halved vs 1024 blocks.
__global__ __launch_bounds__(256) void k_ei(
    const float* __restrict__ image,
    const float* __restrict__ W0, const float* __restrict__ b0,
    const float* __restrict__ W1, const float* __restrict__ b1,
    const float* __restrict__ W2, const float* __restrict__ b2,
    float* __restrict__ dE,          // padded (B, 513, 42) f32
    float* __restrict__ eiF,         // (B*512) f32
    float* __restrict__ outEi)       // f32 output Ei (B*512)
{
    __shared__ float W0s[H1 * 43];
    __shared__ float W1s[H2 * 65];
    __shared__ float W2s[H2];
    __shared__ float b0s[H1];
    __shared__ float b1s[H2];
    __shared__ float xs[8][44];
    __shared__ float h0s[4][2][H1];
    __shared__ float g1s[4][2][H2];
    __shared__ float g0s[4][2][H1];

    const int tid   = threadIdx.x;
    const int w     = tid >> 6;            // wave id 0..3
    const int lane  = tid & 63;
    const int gbase = blockIdx.x * 8;      // first atom of block
    const int ga0   = gbase + w * 2;       // first atom of this wave
    const int b     = ga0 >> 9;
    const int t     = (blockIdx.x >> 5) & 1;   // type, block-uniform (8*32 = 256)

    for (int e = tid; e < H1 * NFEAT; e += 256) {
        int r = e / NFEAT, c = e - r * NFEAT;
        W0s[r * 43 + c] = W0[t * (H1 * NFEAT) + e];
    }
    for (int e = tid; e < H2 * H1; e += 256) {
        int r = e >> 6, c = e & 63;
        W1s[r * 65 + c] = W1[t * (H2 * H1) + e];
    }
    if (tid < H2) { W2s[tid] = W2[t * H2 + tid]; b1s[tid] = b1[t * H2 + tid]; }
    if (tid >= 64 && tid < 128) b0s[tid - 64] = b0[t * H1 + (tid - 64)];
    for (int e = tid; e < 8 * NFEAT; e += 256) {
        int n = e / NFEAT, f = e - n * NFEAT;
        xs[n][f] = image[(size_t)(gbase + n) * NFEAT + f];
    }
    __syncthreads();

    // layer 1: lane j computes h0[j] for both atoms (one weight load, two FMA)
    float s0 = b0s[lane], s1 = b0s[lane];
    #pragma unroll
    for (int f = 0; f < NFEAT; ++f) {
        float w0 = W0s[lane * 43 + f];
        s0 = fmaf(w0, xs[w * 2][f], s0);
        s1 = fmaf(w0, xs[w * 2 + 1][f], s1);
    }
    const float h0a = tanhf(s0), h0b = tanhf(s1);
    h0s[w][0][lane] = h0a;
    h0s[w][1][lane] = h0b;
    __syncthreads();

    // layer 2: lane k (both half-waves compute k = lane&31; dual accumulators)
    const int k = lane & 31;
    s0 = b1s[k]; s1 = b1s[k];
    #pragma unroll
    for (int j = 0; j < H1; ++j) {
        float w1 = W1s[k * 65 + j];
        s0 = fmaf(w1, h0s[w][0][j], s0);
        s1 = fmaf(w1, h0s[w][1][j], s1);
    }
    const float h1a = tanhf(s0), h1b = tanhf(s1);

    // y = sum_k W2[k]*h1[k] (reduce lower 32 lanes; upper half mirrors)
    float p0 = W2s[k] * h1a;
    float p1 = W2s[k] * h1b;
    #pragma unroll
    for (int off = 16; off > 0; off >>= 1) {
        p0 += __shfl_down(p0, off, 64);
        p1 += __shfl_down(p1, off, 64);
    }
    if (lane == 0) {
        float y0 = p0 + b2[t], y1 = p1 + b2[t];
        eiF[ga0]       = y0;  eiF[ga0 + 1]   = y1;
        outEi[ga0]     = y0;  outEi[ga0 + 1] = y1;
    }

    // backward: lanes 0..31 own atom 0's g1, lanes 32..63 atom 1's (no waste)
    const float h1s = (lane < 32) ? h1a : h1b;
    g1s[w][lane >> 5][k] = W2s[k] * (1.0f - h1s * h1s);
    __syncthreads();

    s0 = 0.0f; s1 = 0.0f;
    #pragma unroll
    for (int kk = 0; kk < H2; ++kk) {
        float w1 = W1s[kk * 65 + lane];
        s0 = fmaf(g1s[w][0][kk], w1, s0);
        s1 = fmaf(g1s[w][1][kk], w1, s1);
    }
    g0s[w][0][lane] = s0 * (1.0f - h0a * h0a);
    g0s[w][1][lane] = s1 * (1.0f - h0b * h0b);
    __syncthreads();

    if (lane < NFEAT) {
        s0 = 0.0f; s1 = 0.0f;
        #pragma unroll
        for (int j = 0; j < H1; ++j) {
            float w0 = W0s[j * 43 + lane];
            s0 = fmaf(g0s[w][0][j], w0, s0);
            s1 = fmaf(g0s[w][1][j], w0, s1);
        }
        size_t base = ((size_t)b * (NATOM + 1) + (ga0 & 511) + 1) * NFEAT + lane;
        dE[base]         = s0;
        dE[base + NFEAT] = s1;
    }

    if ((blockIdx.x & 63) == 0 && tid < NFEAT)
        dE[(size_t)(blockIdx.x >> 6) * (NATOM + 1) * NFEAT + tid] = 0.0f;
}

// ---------------------------------------------------------------- kernel 2
// one block per (b, atom). dfeat streamed with FULLY COALESCED float4 loads
// (lane stride 16 B, nontemporal: keeps the 690 KB dE table L2-resident).
// Mod-3 pair/component misalignment handled statically: float4 j needs
// g[q], g[q+1] with q = j + j/3; product i uses g[q] iff i < 3 - (j%3);
// accumulator target rotates as (k+i)%3, un-rotated by tid%3.
// NEW: first 4 stream rounds are issued into registers BEFORE the gather
// barrier (T14 issue-early): register-destined loads stay in flight across
// __syncthreads, hiding the L2 gather round-trip under the HBM stream.
__global__ __launch_bounds__(256) void k_force(
    const float* __restrict__ dfeat,
    const int* __restrict__ neighbor,
    const float* __restrict__ dE,
    const float* __restrict__ eiF,
    float* __restrict__ out)         // f32 output buffer, 16392 elems
{
    __shared__ float g[NNEIGH * NFEAT];   // 4200 f32 = 16.8 KB
    __shared__ int nb[NNEIGH];
    __shared__ float red[12];

    const int ba  = blockIdx.x;          // 0..4095
    const int b   = ba >> 9;
    const int tid = threadIdx.x;

    const float* __restrict__ df = dfeat + (size_t)ba * (NNEIGH * NFEAT * 3);
    const vf4* __restrict__ df4 = (const vf4*)df;

    if (tid < NNEIGH) nb[tid] = neighbor[(size_t)ba * NNEIGH + tid];

    // issue-early prefetch of rounds 0..3 (16 VGPRs; in flight across barrier)
    vf4 pf0 = __builtin_nontemporal_load(df4 + tid);
    vf4 pf1 = __builtin_nontemporal_load(df4 + tid + 256);
    vf4 pf2 = __builtin_nontemporal_load(df4 + tid + 512);
    vf4 pf3 = __builtin_nontemporal_load(df4 + tid + 768);

    __syncthreads();

    // gather dE rows of the 100 neighbors into LDS (flat [n*42+f])
    const float* __restrict__ dEb = dE + (size_t)b * (NATOM + 1) * NFEAT;
    for (int e = tid; e < NNEIGH * NFEAT; e += 256) {
        int n = e / NFEAT;
        int f = e - n * NFEAT;
        g[e] = dEb[(size_t)nb[n] * NFEAT + f];
    }
    __syncthreads();

    // ---- per-lane mod-3 precompute (period 3 in the unrolled k) ----
    const int tid3 = tid % 3;
    int  qm[3];
    bool sel1[3], sel2[3];
    #pragma unroll
    for (int m = 0; m < 3; ++m) {
        int j = tid + 256 * m;
        int r = (tid3 + m) % 3;           // == j % 3 since 256 % 3 == 1
        qm[m]   = j + (j - r) / 3;        // q = j + floor(j/3)
        sel1[m] = (r < 2);                // product i=1 uses g[q] ?
        sel2[m] = (r == 0);               // product i=2 uses g[q] ?
    }

    // ---- stream: 3150 float4 per block; 12 full rounds + 78-thread tail
    float c0 = 0.f, c1 = 0.f, c2 = 0.f;
    #pragma unroll
    for (int k = 0; k < 12; ++k) {
        const int m = k % 3;
        vf4 v;
        if      (k == 0) v = pf0;
        else if (k == 1) v = pf1;
        else if (k == 2) v = pf2;
        else if (k == 3) v = pf3;
        else             v = __builtin_nontemporal_load(df4 + tid + 256 * k);
        int q = qm[m] + (k / 3) * 1024;
        float gq = g[q], gq1 = g[q + 1];
        float s1 = sel1[m] ? gq : gq1;
        float s2 = sel2[m] ? gq : gq1;
        float p0 = gq * v.x, p1 = s1 * v.y, p2 = s2 * v.z, p3 = gq1 * v.w;
        if (m == 0) { c0 += p0; c1 += p1; c2 += p2; c0 += p3; }
        if (m == 1) { c1 += p0; c2 += p1; c0 += p2; c1 += p3; }
        if (m == 2) { c2 += p0; c0 += p1; c1 += p2; c2 += p3; }
    }
    if (tid < 3150 - 3072) {   // tail round k=12 (m=0)
        vf4 v = __builtin_nontemporal_load(df4 + tid + 3072);
        int q = qm[0] + 4096;
        float gq = g[q], gq1 = g[q + 1];
        float s1 = sel1[0] ? gq : gq1;
        float s2 = sel2[0] ? gq : gq1;
        c0 += gq * v.x; c1 += s1 * v.y; c2 += s2 * v.z; c0 += gq1 * v.w;
    }

    // un-rotate: c_m holds force component (tid3 + m) % 3
    float a0, a1, a2;
    if (tid3 == 0)      { a0 = c0; a1 = c1; a2 = c2; }
    else if (tid3 == 1) { a1 = c0; a2 = c1; a0 = c2; }
    else                { a2 = c0; a0 = c1; a1 = c2; }

    // wave shuffle reduce (width 64), then cross-wave via LDS
    #pragma unroll
    for (int off = 32; off > 0; off >>= 1) {
        a0 += __shfl_down(a0, off, 64);
        a1 += __shfl_down(a1, off, 64);
        a2 += __shfl_down(a2, off, 64);
    }
    const int wave = tid >> 6, lane = tid & 63;
    if (lane == 0) { red[wave * 3] = a0; red[wave * 3 + 1] = a1; red[wave * 3 + 2] = a2; }
    __syncthreads();
    if (tid < 3) {
        float s = red[tid] + red[3 + tid] + red[6 + tid] + red[9 + tid];
        out[8 + BQ * NATOM + (size_t)ba * 3 + tid] = s;
    }

    // block 0 additionally reduces Etot (8 values) from f32 Ei in ws
    if (blockIdx.x == 0) {
        for (int bb = wave * 2; bb < wave * 2 + 2; ++bb) {
            float s = 0.f;
            for (int i = lane; i < NATOM; i += 64) s += eiF[bb * NATOM + i];
            #pragma unroll
            for (int off = 32; off > 0; off >>= 1) s += __shfl_down(s, off, 64);
            if (lane == 0) out[bb] = s;
        }
    }
}

// ---------------------------------------------------------------- launcher
extern "C" void kernel_launch(void* const* d_in, const int* in_sizes, int n_in,
                              void* d_out, int out_size, void* d_ws, size_t ws_size,
                              hipStream_t stream)
{
    const float* image    = (const float*)d_in[0];
    const float* dfeat    = (const float*)d_in[1];
    const int*   neighbor = (const int*)d_in[2];
    // d_in[3] natoms_img unused
    const float* W0 = (const float*)d_in[4];
    const float* b0 = (const float*)d_in[5];
    const float* W1 = (const float*)d_in[6];
    const float* b1 = (const float*)d_in[7];
    const float* W2 = (const float*)d_in[8];
    const float* b2 = (const float*)d_in[9];

    float* wsf  = (float*)d_ws;
    float* dE   = wsf + WS_DE;
    float* eiF  = wsf + WS_EI;
    float* out  = (float*)d_out;

    hipLaunchKernelGGL(k_ei, dim3(512), dim3(256), 0, stream,
                       image, W0, b0, W1, b1, W2, b2, dE, eiF, out + 8);
    hipLaunchKernelGGL(k_force, dim3(4096), dim3(256), 0, stream,
                       dfeat, neighbor, dE, eiF, out);
}